// Round 10
// baseline (178.409 us; speedup 1.0000x reference)
//
#include <hip/hip_runtime.h>
#include <hip/hip_bf16.h>
#include <stdint.h>

typedef __attribute__((ext_vector_type(8))) _Float16 f16x8;
typedef __attribute__((ext_vector_type(4))) float f32x4;

static constexpr int BATCH = 4;
static constexpr int SEQ = 4096;
static constexpr int DIM = 64;
static constexpr int QB = 64;                           // q-rows per block
static constexpr int NQB = SEQ / QB;                    // 64
static constexpr uint32_t KEEP_THRESH = 0xCCCCCE00u;    // uniform(bits) < 0.8f
static constexpr float LOG2E = 1.44269504088896340736f;

// per partial-block bytes: onum 64x64 f32 + ml 64x2 f32
static constexpr size_t PB_BYTES = (QB * 64 + QB * 2) * 4;   // 16896
static __host__ __device__ constexpr size_t ws_need(int ns) {
  return (size_t)BATCH * NQB * ns * PB_BYTES;
}
static __host__ __device__ constexpr size_t onum_bytes(int ns) {
  return (size_t)BATCH * NQB * ns * QB * 64 * 4;
}

// XOR-swizzled LDS addressing: 64-elem fp16 rows (128B), swizzle bits 4-6
__device__ __forceinline__ int lds_swz(int row, int colbyte) {
  return row * 128 + (colbyte ^ ((row & 7) << 4));
}

#define ROTL(x, r) (__builtin_amdgcn_alignbit((x), (x), 32 - (r)))

// JAX threefry2x32, key (0,42), counter (0,j), partitionable fold o0^o1; keep iff < 0.8
// caller passes j42 = j + 42 (first key-add folded into the row base)
__device__ __forceinline__ bool tf_keep(uint32_t j42) {
  const uint32_t k1 = 42u;
  const uint32_t k2 = 0x1BD11BDAu ^ k1;
  uint32_t x1 = j42;
  uint32_t x0 = x1;                       // round-1 add folded (k0 = 0, c0 = 0)
  x1 = ROTL(x1, 13) ^ x0;
  x0 += x1; x1 = ROTL(x1, 15) ^ x0;
  x0 += x1; x1 = ROTL(x1, 26) ^ x0;
  x0 += x1; x1 = ROTL(x1, 6)  ^ x0;
  x0 += k1;      x1 += k2 + 1u;
  x0 += x1; x1 = ROTL(x1, 17) ^ x0;
  x0 += x1; x1 = ROTL(x1, 29) ^ x0;
  x0 += x1; x1 = ROTL(x1, 16) ^ x0;
  x0 += x1; x1 = ROTL(x1, 24) ^ x0;
  x0 += k2;      x1 += 2u;
  x0 += x1; x1 = ROTL(x1, 13) ^ x0;
  x0 += x1; x1 = ROTL(x1, 15) ^ x0;
  x0 += x1; x1 = ROTL(x1, 26) ^ x0;
  x0 += x1; x1 = ROTL(x1, 6)  ^ x0;
  /* x0 += 0 */  x1 += k1 + 3u;
  x0 += x1; x1 = ROTL(x1, 17) ^ x0;
  x0 += x1; x1 = ROTL(x1, 29) ^ x0;
  x0 += x1; x1 = ROTL(x1, 16) ^ x0;
  x0 += x1; x1 = ROTL(x1, 24) ^ x0;
  x0 += k1;      x1 += k2 + 4u;
  x0 += x1; x1 = ROTL(x1, 13) ^ x0;
  x0 += x1; x1 = ROTL(x1, 15) ^ x0;
  x0 += x1; x1 = ROTL(x1, 26) ^ x0;
  x0 += x1; x1 = ROTL(x1, 6)  ^ x0;
  x0 += k2;      x1 += 5u;
  return (x0 ^ x1) < KEEP_THRESH;
}

// raw v_exp_f32: D = 2^S0
__device__ __forceinline__ float fexp2(float x) {
  float r;
  asm("v_exp_f32 %0, %1" : "=v"(r) : "v"(x));
  return r;
}

// DPP cross-lane (within 16-lane rows): VALU-latency reduction
template<int CTRL>
__device__ __forceinline__ float dpp_movf(float x) {
  return __int_as_float(
      __builtin_amdgcn_mov_dpp(__float_as_int(x), CTRL, 0xF, 0xF, true));
}
__device__ __forceinline__ float red16_max(float v) {
  v = fmaxf(v, dpp_movf<0xB1>(v));    // quad_perm xor1
  v = fmaxf(v, dpp_movf<0x4E>(v));    // quad_perm xor2
  v = fmaxf(v, dpp_movf<0x141>(v));   // row_half_mirror
  v = fmaxf(v, dpp_movf<0x140>(v));   // row_mirror
  return v;
}
__device__ __forceinline__ float red16_add(float v) {
  v += dpp_movf<0xB1>(v);
  v += dpp_movf<0x4E>(v);
  v += dpp_movf<0x141>(v);
  v += dpp_movf<0x140>(v);
  return v;
}

template<bool PARTIAL, int NS>
__global__ __launch_bounds__(256, 2) void attn_kernel(
    const float* __restrict__ Q, const float* __restrict__ K, const float* __restrict__ V,
    const uint32_t* __restrict__ scale_raw,
    float* __restrict__ Out, float* __restrict__ onum, float* __restrict__ ml)
{
  __shared__ __align__(16) _Float16 Kld[64 * 64];      // [k][d], swizzled rows (fp16)
  __shared__ __align__(16) _Float16 Vt[64 * 64];       // [d][k], swizzled rows
  __shared__ __align__(16) _Float16 Pld[4][16 * 64];   // per-wave P [q16][k64]

  const int b   = blockIdx.y;
  const int q0  = blockIdx.x * QB;
  const int tid = threadIdx.x;
  const int w    = tid >> 6;
  const int lane = tid & 63;
  const int l15  = lane & 15;
  const int l4   = lane >> 4;

  float scale;
  {
    uint32_t sb = *scale_raw;
    int e = (int)((sb >> 23) & 0xFFu);
    if (sb == 0u) scale = 0.0f;
    else if (e == 0 || e == 255) scale = (float)(int)sb;
    else scale = __uint_as_float(sb);
  }
  const float qscale = scale * LOG2E;   // exp2 units

  const int qw = q0 + w * 16;   // this wave's 16 q-rows

  // per-row threefry base with the +42 key-add folded in; rows q = qw + 4*l4 + r
  uint32_t rcb42[4];
#pragma unroll
  for (int r = 0; r < 4; ++r)
    rcb42[r] = ((uint32_t)(b * SEQ + qw + 4 * l4 + r)) * (uint32_t)SEQ + 42u;

  // Q fragment (fp16, qscale folded in)
  f16x8 aq[2];
#pragma unroll
  for (int c = 0; c < 2; ++c) {
    const float* qp = Q + ((size_t)(b * SEQ + qw + l15)) * DIM + l4 * 8 + 32 * c;
    f16x8 h;
#pragma unroll
    for (int j = 0; j < 8; ++j) h[j] = (_Float16)(qp[j] * qscale);
    aq[c] = h;
  }

  float m_r[4], l_p[4];                 // running max (log2 units), per-LANE l partials
  f32x4 Oacc[4];
#pragma unroll
  for (int r = 0; r < 4; ++r) { m_r[r] = -INFINITY; l_p[r] = 0.0f; }
#pragma unroll
  for (int n = 0; n < 4; ++n) Oacc[n] = f32x4{0.f, 0.f, 0.f, 0.f};

  const int nt = PARTIAL ? (SEQ / 64) / NS : SEQ / 64;
  const int t0 = PARTIAL ? (int)blockIdx.z * nt : 0;

  // staging thread maps
  const int kr  = tid >> 4;            // K: row 0..15 (+16i)
  const int kd0 = (tid & 15) * 4;      // K: d-offset
  const int vd  = tid & 63;            // V: column d
  const int vq  = tid >> 6;            // V: k-quad

  for (int kt = 0; kt < nt; ++kt) {
    const int kbase = (t0 + kt) * 64;
    __syncthreads();   // previous tile's LDS reads complete before overwrite
    // ---- stage K (row-major fp16, swizzled, RTE casts) ----
#pragma unroll
    for (int i = 0; i < 4; ++i) {
      int k = kr + 16 * i;
      float4 kf = *(const float4*)(K + ((size_t)(b * SEQ + kbase + k)) * DIM + kd0);
      _Float16 h0 = (_Float16)kf.x, h1 = (_Float16)kf.y,
               h2 = (_Float16)kf.z, h3 = (_Float16)kf.w;
      *(ushort4*)((char*)Kld + lds_swz(k, kd0 * 2)) = ushort4{
        __builtin_bit_cast(unsigned short, h0), __builtin_bit_cast(unsigned short, h1),
        __builtin_bit_cast(unsigned short, h2), __builtin_bit_cast(unsigned short, h3)};
    }
    // ---- stage V transposed (coalesced column loads, packed RTZ cvt) ----
#pragma unroll
    for (int i = 0; i < 4; ++i) {
      int k0 = vq * 4 + 16 * i;
      const float* vp = V + ((size_t)(b * SEQ + kbase + k0)) * DIM + vd;
      float v0 = vp[0], v1 = vp[DIM], v2 = vp[2 * DIM], v3 = vp[3 * DIM];
      unsigned int p01 = __builtin_bit_cast(unsigned int, __builtin_amdgcn_cvt_pkrtz(v0, v1));
      unsigned int p23 = __builtin_bit_cast(unsigned int, __builtin_amdgcn_cvt_pkrtz(v2, v3));
      *(uint2*)((char*)Vt + lds_swz(vd, k0 * 2)) = uint2{p01, p23};
    }
    __syncthreads();

    // ---- S = Qs K^T (fp16, exp2 units) ----
    f32x4 s[4];
#pragma unroll
    for (int n = 0; n < 4; ++n) {
      f32x4 acc = f32x4{0.f, 0.f, 0.f, 0.f};
#pragma unroll
      for (int c = 0; c < 2; ++c) {
        int off = lds_swz(16 * n + l15, (l4 * 8 + 32 * c) * 2);
        f16x8 bk = *(const f16x8*)((char*)Kld + off);
        acc = __builtin_amdgcn_mfma_f32_16x16x32_f16(aq[c], bk, acc, 0, 0, 0);
      }
      s[n] = acc;
    }

    // ---- row max over 64 cols (DPP 16-lane reduction) ----
    float mnew[4];
#pragma unroll
    for (int r = 0; r < 4; ++r)
      mnew[r] = red16_max(fmaxf(fmaxf(s[0][r], s[1][r]), fmaxf(s[2][r], s[3][r])));

    // unconditional rescale
#pragma unroll
    for (int r = 0; r < 4; ++r) {
      float mn = fmaxf(m_r[r], mnew[r]);
      float corr = fexp2(m_r[r] - mn);   // first tile: 2^(-inf)=0
      m_r[r] = mn;
      l_p[r] *= corr;
#pragma unroll
      for (int n = 0; n < 4; ++n) Oacc[n][r] *= corr;
    }

    // ---- e = 2^(s-m); denom (l_p) per-lane unmasked; P masked; write P to LDS ----
    char* pw = (char*)&Pld[w][0];
#pragma unroll
    for (int n = 0; n < 4; ++n) {
      uint32_t cb = (uint32_t)(kbase + l15 + 16 * n);
#pragma unroll
      for (int r = 0; r < 4; ++r) {
        float e = fexp2(s[n][r] - m_r[r]);
        l_p[r] += e;
        float p = tf_keep(rcb42[r] + cb) ? e : 0.0f;
        *(_Float16*)(pw + lds_swz(4 * l4 + r, (l15 + 16 * n) * 2)) = (_Float16)p;
      }
    }

    // wave-local ordering: P writes before P reads
    asm volatile("s_waitcnt lgkmcnt(0)" ::: "memory");
    __builtin_amdgcn_sched_barrier(0);

    // ---- PV: O += P[16x64] * V[64x64] ----
    f16x8 pa[2];
#pragma unroll
    for (int c = 0; c < 2; ++c)
      pa[c] = *(const f16x8*)(pw + lds_swz(l15, (l4 * 8 + 32 * c) * 2));
#pragma unroll
    for (int n = 0; n < 4; ++n) {
#pragma unroll
      for (int c = 0; c < 2; ++c) {
        f16x8 bv = *(const f16x8*)((char*)Vt + lds_swz(l15 + 16 * n, (l4 * 8 + 32 * c) * 2));
        Oacc[n] = __builtin_amdgcn_mfma_f32_16x16x32_f16(pa[c], bv, Oacc[n], 0, 0, 0);
      }
    }
  }

  if (PARTIAL) {
    const int pb = ((b * NQB + (int)blockIdx.x) * NS + (int)blockIdx.z);
    float* op = onum + (size_t)pb * (QB * 64);
#pragma unroll
    for (int r = 0; r < 4; ++r) {
      int row = w * 16 + 4 * l4 + r;           // 0..63
      float lr = red16_add(l_p[r]);
#pragma unroll
      for (int n = 0; n < 4; ++n)
        op[row * 64 + l15 + 16 * n] = Oacc[n][r];
      if (l15 == 0) {
        ml[(size_t)pb * (QB * 2) + row * 2 + 0] = m_r[r];
        ml[(size_t)pb * (QB * 2) + row * 2 + 1] = lr;
      }
    }
  } else {
#pragma unroll
    for (int r = 0; r < 4; ++r) {
      float L = red16_add(l_p[r]);
      float inv = 1.0f / (L * 0.8f);
      int qg = qw + 4 * l4 + r;
      float* op = Out + ((size_t)(b * SEQ + qg)) * DIM + l15;
#pragma unroll
      for (int n = 0; n < 4; ++n)
        op[16 * n] = Oacc[n][r] * inv;
    }
  }
}

template<int NS>
__global__ __launch_bounds__(256) void combine_kernel(
    const float* __restrict__ onum, const float* __restrict__ ml, float* __restrict__ Out)
{
  const int w = threadIdx.x >> 6;
  const int lane = threadIdx.x & 63;
  const int rid = blockIdx.x * 4 + w;          // 0..16383
  const int b = rid >> 12;
  const int qrow = rid & 4095;
  const int qb = qrow >> 6;
  const int r64 = qrow & 63;
  const int pb0 = (b * NQB + qb) * NS;

  float m[NS], l[NS];
  float M = -INFINITY;
#pragma unroll
  for (int s = 0; s < NS; ++s) {
    m[s] = ml[(size_t)(pb0 + s) * (QB * 2) + r64 * 2 + 0];
    l[s] = ml[(size_t)(pb0 + s) * (QB * 2) + r64 * 2 + 1];
    M = fmaxf(M, m[s]);
  }
  float L = 0.0f, acc = 0.0f;
#pragma unroll
  for (int s = 0; s < NS; ++s) {
    float sc = fexp2(m[s] - M);                // log2 units
    L += l[s] * sc;
    acc += onum[(size_t)(pb0 + s) * (QB * 64) + r64 * 64 + lane] * sc;
  }
  Out[(size_t)rid * 64 + lane] = acc / (L * 0.8f);
}

extern "C" void kernel_launch(void* const* d_in, const int* in_sizes, int n_in,
                              void* d_out, int out_size, void* d_ws, size_t ws_size,
                              hipStream_t stream) {
  const float* Q = (const float*)d_in[0];
  const float* K = (const float*)d_in[1];
  const float* V = (const float*)d_in[2];
  const uint32_t* scale_raw = (const uint32_t*)d_in[3];
  float* Out = (float*)d_out;

  if (ws_size >= ws_need(8)) {
    float* onum = (float*)d_ws;
    float* ml = (float*)((char*)d_ws + onum_bytes(8));
    attn_kernel<true, 8><<<dim3(NQB, BATCH, 8), 256, 0, stream>>>(
        Q, K, V, scale_raw, nullptr, onum, ml);
    combine_kernel<8><<<SEQ * BATCH / 4, 256, 0, stream>>>(onum, ml, Out);
  } else if (ws_size >= ws_need(4)) {
    float* onum = (float*)d_ws;
    float* ml = (float*)((char*)d_ws + onum_bytes(4));
    attn_kernel<true, 4><<<dim3(NQB, BATCH, 4), 256, 0, stream>>>(
        Q, K, V, scale_raw, nullptr, onum, ml);
    combine_kernel<4><<<SEQ * BATCH / 4, 256, 0, stream>>>(onum, ml, Out);
  } else {
    attn_kernel<false, 1><<<dim3(NQB, BATCH, 1), 256, 0, stream>>>(
        Q, K, V, scale_raw, Out, nullptr, nullptr);
  }
}

// Round 11
// 171.366 us; speedup vs baseline: 1.0411x; 1.0411x over previous
//
#include <hip/hip_runtime.h>
#include <hip/hip_bf16.h>
#include <stdint.h>

typedef __attribute__((ext_vector_type(8))) _Float16 f16x8;
typedef __attribute__((ext_vector_type(4))) float f32x4;

static constexpr int BATCH = 4;
static constexpr int SEQ = 4096;
static constexpr int DIM = 64;
static constexpr uint32_t KEEP_THRESH = 0xCCCCCE00u;   // uniform(bits) < 0.8f

// per partial-block bytes: onum 64x64 f32 + ml 64x2 f32
static constexpr size_t PB_BYTES = (64 * 64 + 128) * 4;   // 16896
static __host__ __device__ constexpr size_t ws_need(int ns) {
  return (size_t)BATCH * 64 * ns * PB_BYTES;
}
static __host__ __device__ constexpr size_t onum_bytes(int ns) {
  return (size_t)BATCH * 64 * ns * 64 * 64 * 4;
}

// XOR-swizzled LDS addressing: 64-elem fp16 rows (128B), swizzle bits 4-6
__device__ __forceinline__ int lds_swz(int row, int colbyte) {
  return row * 128 + (colbyte ^ ((row & 7) << 4));
}

#define ROTL(x, r) (__builtin_amdgcn_alignbit((x), (x), 32 - (r)))

// JAX threefry2x32, key (0,42), counter (0,j), partitionable fold o0^o1; keep iff < 0.8
// caller passes j42 = j + 42 (first key-add folded into the row base)
__device__ __forceinline__ bool tf_keep(uint32_t j42) {
  const uint32_t k1 = 42u;
  const uint32_t k2 = 0x1BD11BDAu ^ k1;
  uint32_t x1 = j42;
  uint32_t x0 = x1;                       // round-1 add folded (k0 = 0, c0 = 0)
  x1 = ROTL(x1, 13) ^ x0;
  x0 += x1; x1 = ROTL(x1, 15) ^ x0;
  x0 += x1; x1 = ROTL(x1, 26) ^ x0;
  x0 += x1; x1 = ROTL(x1, 6)  ^ x0;
  x0 += k1;      x1 += k2 + 1u;
  x0 += x1; x1 = ROTL(x1, 17) ^ x0;
  x0 += x1; x1 = ROTL(x1, 29) ^ x0;
  x0 += x1; x1 = ROTL(x1, 16) ^ x0;
  x0 += x1; x1 = ROTL(x1, 24) ^ x0;
  x0 += k2;      x1 += 2u;
  x0 += x1; x1 = ROTL(x1, 13) ^ x0;
  x0 += x1; x1 = ROTL(x1, 15) ^ x0;
  x0 += x1; x1 = ROTL(x1, 26) ^ x0;
  x0 += x1; x1 = ROTL(x1, 6)  ^ x0;
  /* x0 += 0 */  x1 += k1 + 3u;
  x0 += x1; x1 = ROTL(x1, 17) ^ x0;
  x0 += x1; x1 = ROTL(x1, 29) ^ x0;
  x0 += x1; x1 = ROTL(x1, 16) ^ x0;
  x0 += x1; x1 = ROTL(x1, 24) ^ x0;
  x0 += k1;      x1 += k2 + 4u;
  x0 += x1; x1 = ROTL(x1, 13) ^ x0;
  x0 += x1; x1 = ROTL(x1, 15) ^ x0;
  x0 += x1; x1 = ROTL(x1, 26) ^ x0;
  x0 += x1; x1 = ROTL(x1, 6)  ^ x0;
  x0 += k2;      x1 += 5u;
  return (x0 ^ x1) < KEEP_THRESH;
}

// DPP cross-lane (within 16-lane rows): fast VALU-latency reduction
template<int CTRL>
__device__ __forceinline__ float dpp_movf(float x) {
  return __int_as_float(
      __builtin_amdgcn_mov_dpp(__float_as_int(x), CTRL, 0xF, 0xF, true));
}
__device__ __forceinline__ float red16_max(float v) {
  v = fmaxf(v, dpp_movf<0xB1>(v));    // quad_perm xor1
  v = fmaxf(v, dpp_movf<0x4E>(v));    // quad_perm xor2
  v = fmaxf(v, dpp_movf<0x141>(v));   // row_half_mirror
  v = fmaxf(v, dpp_movf<0x140>(v));   // row_mirror
  return v;
}
__device__ __forceinline__ float red16_add(float v) {
  v += dpp_movf<0xB1>(v);
  v += dpp_movf<0x4E>(v);
  v += dpp_movf<0x141>(v);
  v += dpp_movf<0x140>(v);
  return v;
}

template<bool PARTIAL, int NS>
__global__ __launch_bounds__(256, 2) void attn_kernel(
    const float* __restrict__ Q, const float* __restrict__ K, const float* __restrict__ V,
    const uint32_t* __restrict__ scale_raw,
    float* __restrict__ Out, float* __restrict__ onum, float* __restrict__ ml)
{
  __shared__ __align__(16) _Float16 Kld[64 * 64];      // [k][d], swizzled rows (fp16)
  __shared__ __align__(16) _Float16 Vt[64 * 64];       // [d][k], swizzled rows
  __shared__ __align__(16) _Float16 Pld[4][16 * 64];   // per-wave P transpose

  const int b   = blockIdx.y;
  const int q0  = blockIdx.x * 64;
  const int tid = threadIdx.x;
  const int w    = tid >> 6;
  const int lane = tid & 63;
  const int l15  = lane & 15;
  const int l4   = lane >> 4;

  float scale;
  {
    uint32_t sb = *scale_raw;
    int e = (int)((sb >> 23) & 0xFFu);
    if (sb == 0u) scale = 0.0f;
    else if (e == 0 || e == 255) scale = (float)(int)sb;
    else scale = __uint_as_float(sb);
  }

  const int qw = q0 + w * 16;

  // per-row threefry base with the +42 key-add folded in
  uint32_t rcb42[4];
#pragma unroll
  for (int r = 0; r < 4; ++r)
    rcb42[r] = ((uint32_t)(b * SEQ + qw + 4 * l4 + r)) * (uint32_t)SEQ + 42u;

  // Q fragments, scale folded in, split fp16 hi/lo (K stays single fp16;
  // S = qh*k + ql*k so QK error is K-rounding only, ~4e-3)
  f16x8 aqh[2], aql[2];
#pragma unroll
  for (int c = 0; c < 2; ++c) {
    const float* qp = Q + ((size_t)(b * SEQ + qw + l15)) * DIM + l4 * 8 + 32 * c;
    f16x8 h, l;
#pragma unroll
    for (int j = 0; j < 8; ++j) {
      float f = qp[j] * scale;
      _Float16 fh = (_Float16)f;
      h[j] = fh;
      l[j] = (_Float16)(f - (float)fh);
    }
    aqh[c] = h; aql[c] = l;
  }

  float m_r[4], l_r[4];
  f32x4 Oacc[4];
#pragma unroll
  for (int r = 0; r < 4; ++r) { m_r[r] = -INFINITY; l_r[r] = 0.0f; }
#pragma unroll
  for (int n = 0; n < 4; ++n) Oacc[n] = f32x4{0.f, 0.f, 0.f, 0.f};

  const int nt = PARTIAL ? (SEQ / 64) / NS : SEQ / 64;
  const int t0 = PARTIAL ? (int)blockIdx.z * nt : 0;

  // staging thread maps
  const int kr  = tid >> 4;            // K: row 0..15 (+16i)
  const int kd0 = (tid & 15) * 4;      // K: d-offset
  const int vd  = tid & 63;            // V: column d
  const int vq  = tid >> 6;            // V: k-quad

  for (int kt = 0; kt < nt; ++kt) {
    const int kbase = (t0 + kt) * 64;
    __syncthreads();   // previous tile's LDS reads complete before overwrite
    // ---- stage K (row-major fp16, swizzled, RTE casts) ----
#pragma unroll
    for (int i = 0; i < 4; ++i) {
      int k = kr + 16 * i;
      float4 kf = *(const float4*)(K + ((size_t)(b * SEQ + kbase + k)) * DIM + kd0);
      _Float16 h0 = (_Float16)kf.x, h1 = (_Float16)kf.y,
               h2 = (_Float16)kf.z, h3 = (_Float16)kf.w;
      *(ushort4*)((char*)Kld + lds_swz(k, kd0 * 2)) = ushort4{
        __builtin_bit_cast(unsigned short, h0), __builtin_bit_cast(unsigned short, h1),
        __builtin_bit_cast(unsigned short, h2), __builtin_bit_cast(unsigned short, h3)};
    }
    // ---- stage V transposed (coalesced column loads, packed RTZ cvt) ----
#pragma unroll
    for (int i = 0; i < 4; ++i) {
      int k0 = vq * 4 + 16 * i;
      const float* vp = V + ((size_t)(b * SEQ + kbase + k0)) * DIM + vd;
      float v0 = vp[0], v1 = vp[DIM], v2 = vp[2 * DIM], v3 = vp[3 * DIM];
      unsigned int p01 = __builtin_bit_cast(unsigned int, __builtin_amdgcn_cvt_pkrtz(v0, v1));
      unsigned int p23 = __builtin_bit_cast(unsigned int, __builtin_amdgcn_cvt_pkrtz(v2, v3));
      *(uint2*)((char*)Vt + lds_swz(vd, k0 * 2)) = uint2{p01, p23};
    }
    __syncthreads();

    // ---- S = Qs K^T, Q-split fp16: qh*k + ql*k ----
    f32x4 s[4];
#pragma unroll
    for (int n = 0; n < 4; ++n) {
      f32x4 acc = f32x4{0.f, 0.f, 0.f, 0.f};
#pragma unroll
      for (int c = 0; c < 2; ++c) {
        int off = lds_swz(16 * n + l15, (l4 * 8 + 32 * c) * 2);
        f16x8 bk = *(const f16x8*)((char*)Kld + off);
        acc = __builtin_amdgcn_mfma_f32_16x16x32_f16(aqh[c], bk, acc, 0, 0, 0);
        acc = __builtin_amdgcn_mfma_f32_16x16x32_f16(aql[c], bk, acc, 0, 0, 0);
      }
      s[n] = acc;
    }

    // ---- fused dropout mask -> float 0/1 regs ----
    float fm[4][4];
#pragma unroll
    for (int n = 0; n < 4; ++n) {
      uint32_t cb = (uint32_t)(kbase + l15 + 16 * n);
#pragma unroll
      for (int r = 0; r < 4; ++r)
        fm[n][r] = tf_keep(rcb42[r] + cb) ? 1.0f : 0.0f;
    }

    // ---- row max over 64 cols (DPP 16-lane reduction, VALU latency) ----
    float mnew[4];
#pragma unroll
    for (int r = 0; r < 4; ++r)
      mnew[r] = red16_max(fmaxf(fmaxf(s[0][r], s[1][r]), fmaxf(s[2][r], s[3][r])));

    // exact defer-rescale: only rescale if some row's max grew
    bool grow = (mnew[0] > m_r[0]) | (mnew[1] > m_r[1]) |
                (mnew[2] > m_r[2]) | (mnew[3] > m_r[3]);
    if (__any(grow)) {
#pragma unroll
      for (int r = 0; r < 4; ++r) {
        float mn = fmaxf(m_r[r], mnew[r]);
        float corr = __expf(m_r[r] - mn);   // first tile: exp(-inf)=0
        m_r[r] = mn;
        l_r[r] *= corr;
#pragma unroll
        for (int n = 0; n < 4; ++n) Oacc[n][r] *= corr;
      }
    }

    // ---- e = exp(s-m); denom unmasked; P masked; write P^T to LDS ----
    float psum[4] = {0.f, 0.f, 0.f, 0.f};
    char* pw = (char*)&Pld[w][0];
#pragma unroll
    for (int n = 0; n < 4; ++n) {
#pragma unroll
      for (int r = 0; r < 4; ++r) {
        float e = __expf(s[n][r] - m_r[r]);
        psum[r] += e;
        float p = e * fm[n][r];
        *(_Float16*)(pw + lds_swz(4 * l4 + r, (l15 + 16 * n) * 2)) = (_Float16)p;
      }
    }
#pragma unroll
    for (int r = 0; r < 4; ++r)
      l_r[r] += red16_add(psum[r]);

    // wave-local ordering: P writes before P reads
    asm volatile("s_waitcnt lgkmcnt(0)" ::: "memory");
    __builtin_amdgcn_sched_barrier(0);

    // ---- PV: O += P[16x64] * V[64x64] ----
    f16x8 pa[2];
#pragma unroll
    for (int c = 0; c < 2; ++c)
      pa[c] = *(const f16x8*)(pw + lds_swz(l15, (l4 * 8 + 32 * c) * 2));
#pragma unroll
    for (int n = 0; n < 4; ++n) {
#pragma unroll
      for (int c = 0; c < 2; ++c) {
        f16x8 bv = *(const f16x8*)((char*)Vt + lds_swz(l15 + 16 * n, (l4 * 8 + 32 * c) * 2));
        Oacc[n] = __builtin_amdgcn_mfma_f32_16x16x32_f16(pa[c], bv, Oacc[n], 0, 0, 0);
      }
    }
  }

  if (PARTIAL) {
    const int pb = ((b * 64 + (int)blockIdx.x) * NS + (int)blockIdx.z);
    float* op = onum + (size_t)pb * 4096;
#pragma unroll
    for (int r = 0; r < 4; ++r) {
      int row64 = w * 16 + 4 * l4 + r;
#pragma unroll
      for (int n = 0; n < 4; ++n)
        op[row64 * 64 + l15 + 16 * n] = Oacc[n][r];
      if (l15 == 0) {
        ml[(size_t)pb * 128 + row64 * 2 + 0] = m_r[r];
        ml[(size_t)pb * 128 + row64 * 2 + 1] = l_r[r];
      }
    }
  } else {
#pragma unroll
    for (int r = 0; r < 4; ++r) {
      float inv = 1.0f / (l_r[r] * 0.8f);
      int qg = qw + 4 * l4 + r;
      float* op = Out + ((size_t)(b * SEQ + qg)) * DIM + l15;
#pragma unroll
      for (int n = 0; n < 4; ++n)
        op[16 * n] = Oacc[n][r] * inv;
    }
  }
}

template<int NS>
__global__ __launch_bounds__(256) void combine_kernel(
    const float* __restrict__ onum, const float* __restrict__ ml, float* __restrict__ Out)
{
  const int w = threadIdx.x >> 6;
  const int lane = threadIdx.x & 63;
  const int rid = blockIdx.x * 4 + w;          // 0..16383
  const int b = rid >> 12;
  const int qrow = rid & 4095;
  const int qb = qrow >> 6;
  const int r64 = qrow & 63;
  const int pb0 = (b * 64 + qb) * NS;

  float m[NS], l[NS];
  float M = -INFINITY;
#pragma unroll
  for (int s = 0; s < NS; ++s) {
    m[s] = ml[(size_t)(pb0 + s) * 128 + r64 * 2 + 0];
    l[s] = ml[(size_t)(pb0 + s) * 128 + r64 * 2 + 1];
    M = fmaxf(M, m[s]);
  }
  float L = 0.0f, acc = 0.0f;
#pragma unroll
  for (int s = 0; s < NS; ++s) {
    float sc = __expf(m[s] - M);
    L += l[s] * sc;
    acc += onum[(size_t)(pb0 + s) * 4096 + r64 * 64 + lane] * sc;
  }
  Out[(size_t)rid * 64 + lane] = acc / (L * 0.8f);
}

extern "C" void kernel_launch(void* const* d_in, const int* in_sizes, int n_in,
                              void* d_out, int out_size, void* d_ws, size_t ws_size,
                              hipStream_t stream) {
  const float* Q = (const float*)d_in[0];
  const float* K = (const float*)d_in[1];
  const float* V = (const float*)d_in[2];
  const uint32_t* scale_raw = (const uint32_t*)d_in[3];
  float* Out = (float*)d_out;

  if (ws_size >= ws_need(8)) {
    float* onum = (float*)d_ws;
    float* ml = (float*)((char*)d_ws + onum_bytes(8));
    attn_kernel<true, 8><<<dim3(64, BATCH, 8), 256, 0, stream>>>(
        Q, K, V, scale_raw, nullptr, onum, ml);
    combine_kernel<8><<<SEQ * BATCH / 4, 256, 0, stream>>>(onum, ml, Out);
  } else if (ws_size >= ws_need(4)) {
    float* onum = (float*)d_ws;
    float* ml = (float*)((char*)d_ws + onum_bytes(4));
    attn_kernel<true, 4><<<dim3(64, BATCH, 4), 256, 0, stream>>>(
        Q, K, V, scale_raw, nullptr, onum, ml);
    combine_kernel<4><<<SEQ * BATCH / 4, 256, 0, stream>>>(onum, ml, Out);
  } else {
    attn_kernel<false, 1><<<dim3(64, BATCH, 1), 256, 0, stream>>>(
        Q, K, V, scale_raw, Out, nullptr, nullptr);
  }
}